// Round 1
// baseline (3849.128 us; speedup 1.0000x reference)
//
#include <hip/hip_runtime.h>
#include <math.h>

// Problem constants (from reference setup_inputs)
constexpr int B   = 4;
constexpr int T   = 16;
constexpr int CIN = 32;
constexpr int HID = 64;
constexpr int H   = 64;
constexpr int Wd  = 64;

constexpr int TILE  = 16;       // spatial tile (16x16 output pixels)
constexpr int PADT  = TILE + 2; // 18 (with halo for 3x3, pad=1)
constexpr int NSTG  = 32;       // channels staged per LDS fill
constexpr int CG    = 8;        // hidden channels per block

// Fused ConvGRU step: gi = conv(x_t, Wi), gh = conv(h_{t-1}, Wh), gates, h_t.
// Grid: (4 tiles_x, 4 tiles_y, B*8 channel-groups). Block: (16,16).
__global__ __launch_bounds__(256, 2) void convgru_step(
    const float* __restrict__ x,    // [B,T,CIN,H,W]
    const float* __restrict__ Wi,   // [3*HID, CIN, 3, 3]
    const float* __restrict__ Wh,   // [3*HID, HID, 3, 3]
    const float* __restrict__ hprev_base, // d_out base, or nullptr for t==0
    float* __restrict__ hout_base,  // d_out base
    int t)
{
    __shared__ float tile[NSTG * PADT * PADT]; // 32*18*18*4 = 41472 B

    const int lx = threadIdx.x, ly = threadIdx.y;
    const int tid = ly * TILE + lx;
    const int tx = blockIdx.x, ty = blockIdx.y;
    const int b  = blockIdx.z >> 3;
    const int cg = blockIdx.z & 7;

    const int gx = tx * TILE + lx;
    const int gy = ty * TILE + ly;

    float accR[CG], accZ[CG], accIN[CG], accHN[CG];
    #pragma unroll
    for (int i = 0; i < CG; ++i) { accR[i]=0.f; accZ[i]=0.f; accIN[i]=0.f; accHN[i]=0.f; }

    // ---- LDS staging of a 32-channel chunk with halo + zero pad ----
    auto stage = [&](const float* src /* [ch][H][W] for this image, or null */) {
        for (int i = tid; i < NSTG * PADT * PADT; i += 256) {
            int ic  = i / (PADT * PADT);
            int rem = i - ic * (PADT * PADT);
            int r   = rem / PADT;
            int c   = rem - r * PADT;
            int grow = ty * TILE + r - 1;
            int gcol = tx * TILE + c - 1;
            float v = 0.f;
            if (src != nullptr && (unsigned)grow < (unsigned)H && (unsigned)gcol < (unsigned)Wd)
                v = src[ic * (H * Wd) + grow * Wd + gcol];
            tile[i] = v;
        }
    };

    // ---- accumulate conv over the staged 32 channels ----
    // Wbase: weight tensor [192][wic][3][3]; icbase: global input-channel offset
    auto accum = [&](const float* __restrict__ Wbase, int wic, int icbase, bool isX) {
        const int c0 = cg * CG;
        #pragma unroll 1
        for (int ic = 0; ic < NSTG; ++ic) {
            float v[9];
            #pragma unroll
            for (int dy = 0; dy < 3; ++dy)
                #pragma unroll
                for (int dx = 0; dx < 3; ++dx)
                    v[dy * 3 + dx] = tile[(ic * PADT + (ly + dy)) * PADT + (lx + dx)];
            #pragma unroll
            for (int cc = 0; cc < CG; ++cc) {
                const float* wr = Wbase + ((size_t)((0 * HID + c0 + cc) * wic + icbase + ic)) * 9;
                const float* wz = Wbase + ((size_t)((1 * HID + c0 + cc) * wic + icbase + ic)) * 9;
                const float* wn = Wbase + ((size_t)((2 * HID + c0 + cc) * wic + icbase + ic)) * 9;
                float r = 0.f, z = 0.f, n = 0.f;
                #pragma unroll
                for (int k = 0; k < 9; ++k) {
                    r += v[k] * wr[k];
                    z += v[k] * wz[k];
                    n += v[k] * wn[k];
                }
                accR[cc] += r;
                accZ[cc] += z;
                if (isX) accIN[cc] += n; else accHN[cc] += n;
            }
        }
    };

    // x contribution (32 input channels)
    const float* xb = x + ((size_t)b * T + t) * CIN * H * Wd;
    stage(xb);
    __syncthreads();
    accum(Wi, CIN, 0, true);
    __syncthreads();

    // h contribution (64 channels, staged in two 32-channel chunks)
    const float* hb = (hprev_base != nullptr)
        ? hprev_base + ((size_t)b * T + (t - 1)) * HID * H * Wd
        : nullptr;
    stage(hb);
    __syncthreads();
    accum(Wh, HID, 0, false);
    __syncthreads();
    stage(hb ? hb + (size_t)NSTG * H * Wd : nullptr);
    __syncthreads();
    accum(Wh, HID, NSTG, false);

    // ---- gates + state update ----
    float* ho = hout_base + ((size_t)b * T + t) * HID * H * Wd;
    #pragma unroll
    for (int cc = 0; cc < CG; ++cc) {
        const int c = cg * CG + cc;
        float r = 1.f / (1.f + expf(-accR[cc]));
        float z = 1.f / (1.f + expf(-accZ[cc]));
        float n = tanhf(accIN[cc] + r * accHN[cc]);
        float hv = (hb != nullptr) ? hb[(size_t)c * (H * Wd) + gy * Wd + gx] : 0.f;
        ho[(size_t)c * (H * Wd) + gy * Wd + gx] = (1.f - z) * n + z * hv;
    }
}

extern "C" void kernel_launch(void* const* d_in, const int* in_sizes, int n_in,
                              void* d_out, int out_size, void* d_ws, size_t ws_size,
                              hipStream_t stream) {
    const float* x  = (const float*)d_in[0];
    const float* Wi = (const float*)d_in[1];
    const float* Wh = (const float*)d_in[2];
    float* out = (float*)d_out;

    dim3 grid(H / TILE, Wd / TILE, B * (HID / CG)); // (4,4,32)
    dim3 block(TILE, TILE);

    for (int t = 0; t < T; ++t) {
        const float* hprev = (t == 0) ? nullptr : out;
        convgru_step<<<grid, block, 0, stream>>>(x, Wi, Wh, hprev, out, t);
    }
}

// Round 4
// 397.923 us; speedup vs baseline: 9.6730x; 9.6730x over previous
//
#include <hip/hip_runtime.h>
#include <math.h>

// Problem dims
constexpr int B_  = 4;
constexpr int T_  = 16;
constexpr int CIN = 32;
constexpr int HID = 64;
constexpr int HH  = 64;
constexpr int WW  = 64;
constexpr int HW  = HH * WW; // 4096

// ---------------- MFMA path config ----------------
constexpr int TR = 8,  TC = 16;         // output pixel tile: 8 rows x 16 cols
constexpr int PR = TR + 2, PC = TC + 2; // 10 x 18 (halo)
constexpr int CPAD = 40;                // LDS channel stride (80B)
constexpr int KCH = 32;                 // channels per K-chunk
constexpr int NTILE_ELEM = PR * PC * KCH; // 5760
constexpr int NS  = (NTILE_ELEM + 255) / 256; // 23
constexpr int AKW = 9 * KCH;            // 288 k per chunk (halfwords; 576 B packed)
constexpr int AROWS = 48;               // 3 gates x 16 hidden rows
constexpr int ASLAB = AROWS * AKW;      // 13824 halfwords per (chunk,hg) slab (global, packed)
constexpr int AVEC  = ASLAB / 8;        // 1728 16B vectors
constexpr int NSA   = (AVEC + 255) / 256; // 7
constexpr int ATOTAL = 3 * 4 * ASLAB;   // 165888 elements
constexpr int AROWB = 640;              // LDS A-row stride in BYTES (5x128: XOR-closed pad)

typedef __attribute__((ext_vector_type(8))) short bf16x8;
typedef __attribute__((ext_vector_type(4))) float f32x4;

__device__ inline unsigned short f2bf(float f) {
    union { float f; unsigned u; } v; v.f = f;
    return (unsigned short)((v.u + 0x7FFFu + ((v.u >> 16) & 1u)) >> 16);
}

// One-off: fp32 weights -> bf16, layout [ch][hg][gt][m16][tap][ic32] (packed 576B rows)
__global__ void wconv(const float* __restrict__ Wi, const float* __restrict__ Wh,
                      unsigned short* __restrict__ A2) {
    int idx = blockIdx.x * 256 + threadIdx.x;
    if (idx >= ATOTAL) return;
    int ic  = idx & 31;
    int r1  = idx >> 5;
    int tap = r1 % 9;
    int r2  = r1 / 9;
    int m   = r2 & 15;
    int r3  = r2 >> 4;
    int gt  = r3 % 3;
    int r4  = r3 / 3;
    int hg  = r4 & 3;
    int ch  = r4 >> 2;
    int o   = gt * 64 + hg * 16 + m;
    float w = (ch == 0) ? Wi[(o * CIN + ic) * 9 + tap]
                        : Wh[(o * HID + (ch - 1) * 32 + ic) * 9 + tap];
    A2[idx] = f2bf(w);
}

// Fused ConvGRU step on MFMA.
// grid (32 tiles, 4 hg, 4 b), block 256 (4 waves; wave w owns pixel rows 2w,2w+1).
__global__ __launch_bounds__(256, 2) void convgru_mfma(
    const float* __restrict__ x, const unsigned short* __restrict__ A2,
    const float* hall, float* out, int t)
{
    __shared__ __align__(16) unsigned short tin[PR * PC * CPAD];   // 14400 B
    __shared__ __align__(16) unsigned short Al[AROWS * (AROWB/2)]; // 30720 B (640B rows, XOR-swizzled)

    const int tid  = threadIdx.x;
    const int lane = tid & 63, wave = tid >> 6;
    const int px   = lane & 15, kl = lane >> 4;  // px = A row = B col = C col
    const int ty = blockIdx.x >> 2, tx = blockIdx.x & 3;
    const int hg = blockIdx.y, b = blockIdx.z;
    const int gy0 = ty * TR, gx0 = tx * TC;

    const int nch = (t > 0) ? 3 : 1;
    const float* hb = (t > 0) ? (hall + ((size_t)(b * T_ + t - 1)) * HID * HW) : nullptr;
    const float* xb = x + ((size_t)(b * T_ + t)) * CIN * HW;

    f32x4 accR[2] = {}, accZ[2] = {}, accNX[2] = {}, accNH[2] = {};

    float  ireg[NS];
    bf16x8 areg[NSA];

    auto load_in = [&](int ch) {
        const float* src = (ch == 0) ? xb : (hb + (size_t)(ch - 1) * KCH * HW);
        #pragma unroll
        for (int j = 0; j < NS; ++j) {
            int e = tid + j * 256;
            float v = 0.f;
            if (e < NTILE_ELEM) {
                int ic = e / (PR * PC);
                int rem = e - ic * (PR * PC);
                int r = rem / PC, c = rem - r * PC;
                int gy = gy0 + r - 1, gx = gx0 + c - 1;
                if ((unsigned)gy < (unsigned)HH && (unsigned)gx < (unsigned)WW)
                    v = src[ic * HW + gy * WW + gx];
            }
            ireg[j] = v;
        }
    };
    auto load_A = [&](int ch) {
        const unsigned short* s = A2 + (size_t)(ch * 4 + hg) * ASLAB;
        #pragma unroll
        for (int j = 0; j < NSA; ++j) {
            int v = tid + j * 256;
            if (v < AVEC) areg[j] = *(const bf16x8*)(s + v * 8);
        }
    };
    auto write_in = [&]() {
        #pragma unroll
        for (int j = 0; j < NS; ++j) {
            int e = tid + j * 256;
            if (e < NTILE_ELEM) {
                int ic = e / (PR * PC);
                int rem = e - ic * (PR * PC);
                int r = rem / PC, c = rem - r * PC;
                tin[(r * PC + c) * CPAD + ic] = f2bf(ireg[j]);
            }
        }
    };
    auto write_A = [&]() {
        #pragma unroll
        for (int j = 0; j < NSA; ++j) {
            int v = tid + j * 256;
            if (v < AVEC) {
                int row = v / 36;                 // 36 16B-vectors per logical 576B row
                int kb  = (v - row * 36) * 16;    // packed byte offset in row [0,576)
                // 640B row stride (5x128) keeps kb ^ s inside the row: bijective.
                char* dst = (char*)Al + row * AROWB + (kb ^ ((row & 7) << 4));
                *(bf16x8*)dst = areg[j];
            }
        }
    };

    // B-frag LDS read bases (halfword index); tap adds (dy*PC+dx)*CPAD
    const int rb0 = ((wave * 2 + 0) * PC + px) * CPAD + kl * 8;
    const int rb1 = rb0 + PC * CPAD;
    const int swA = (px & 7) << 4; // rows px, px+16, px+32 share (row&7)

    auto compute = [&](bool isX) {
        #pragma unroll
        for (int tap = 0; tap < 9; ++tap) {
            const int dy = tap / 3, dx = tap - 3 * dy;
            const int toff = (dy * PC + dx) * CPAD;
            bf16x8 b0 = *(const bf16x8*)(tin + rb0 + toff);
            bf16x8 b1 = *(const bf16x8*)(tin + rb1 + toff);
            const char* ab = (const char*)Al + px * AROWB + ((tap * 64 + kl * 16) ^ swA);
            bf16x8 ar = *(const bf16x8*)(ab);
            bf16x8 az = *(const bf16x8*)(ab + 16 * AROWB);
            bf16x8 an = *(const bf16x8*)(ab + 32 * AROWB);
            accR[0] = __builtin_amdgcn_mfma_f32_16x16x32_bf16(ar, b0, accR[0], 0, 0, 0);
            accR[1] = __builtin_amdgcn_mfma_f32_16x16x32_bf16(ar, b1, accR[1], 0, 0, 0);
            accZ[0] = __builtin_amdgcn_mfma_f32_16x16x32_bf16(az, b0, accZ[0], 0, 0, 0);
            accZ[1] = __builtin_amdgcn_mfma_f32_16x16x32_bf16(az, b1, accZ[1], 0, 0, 0);
            if (isX) {
                accNX[0] = __builtin_amdgcn_mfma_f32_16x16x32_bf16(an, b0, accNX[0], 0, 0, 0);
                accNX[1] = __builtin_amdgcn_mfma_f32_16x16x32_bf16(an, b1, accNX[1], 0, 0, 0);
            } else {
                accNH[0] = __builtin_amdgcn_mfma_f32_16x16x32_bf16(an, b0, accNH[0], 0, 0, 0);
                accNH[1] = __builtin_amdgcn_mfma_f32_16x16x32_bf16(an, b1, accNH[1], 0, 0, 0);
            }
        }
    };

    // ---- pipeline: stage chunk0, then per chunk {preload next | compute | write next} ----
    load_in(0); load_A(0);
    write_in(); write_A();
    __syncthreads();
    for (int ch = 0; ch < nch; ++ch) {
        if (ch + 1 < nch) { load_in(ch + 1); load_A(ch + 1); }
        compute(ch == 0);
        __syncthreads();
        if (ch + 1 < nch) { write_in(); write_A(); __syncthreads(); }
    }

    // ---- epilogue: gates + state update (fp32) ----
    float* outp = out + ((size_t)(b * T_ + t)) * HID * HW;
    #pragma unroll
    for (int g = 0; g < 2; ++g) {
        int gy = gy0 + wave * 2 + g;
        int gx = gx0 + px;
        #pragma unroll
        for (int q = 0; q < 4; ++q) {
            int c = hg * 16 + kl * 4 + q;
            float sr = 1.f / (1.f + expf(-accR[g][q]));
            float sz = 1.f / (1.f + expf(-accZ[g][q]));
            float nn = tanhf(accNX[g][q] + sr * accNH[g][q]);
            float hv = hb ? hb[(size_t)c * HW + gy * WW + gx] : 0.f;
            outp[(size_t)c * HW + gy * WW + gx] = (1.f - sz) * nn + sz * hv;
        }
    }
}

// ---------------- verified fp32 fallback (used only if ws too small) ----------------
constexpr int FTILE = 16, FPADT = FTILE + 2, FNSTG = 32, FCG = 8;

__global__ __launch_bounds__(256, 2) void convgru_step(
    const float* __restrict__ x, const float* __restrict__ Wi,
    const float* __restrict__ Wh, const float* hprev_base,
    float* hout_base, int t)
{
    __shared__ float tile[FNSTG * FPADT * FPADT];

    const int lx = threadIdx.x, ly = threadIdx.y;
    const int tid = ly * FTILE + lx;
    const int tx = blockIdx.x, ty = blockIdx.y;
    const int b  = blockIdx.z >> 3;
    const int cg = blockIdx.z & 7;
    const int gx = tx * FTILE + lx;
    const int gy = ty * FTILE + ly;

    float accR[FCG], accZ[FCG], accIN[FCG], accHN[FCG];
    #pragma unroll
    for (int i = 0; i < FCG; ++i) { accR[i]=0.f; accZ[i]=0.f; accIN[i]=0.f; accHN[i]=0.f; }

    auto stage = [&](const float* src) {
        for (int i = tid; i < FNSTG * FPADT * FPADT; i += 256) {
            int ic  = i / (FPADT * FPADT);
            int rem = i - ic * (FPADT * FPADT);
            int r   = rem / FPADT;
            int c   = rem - r * FPADT;
            int grow = ty * FTILE + r - 1;
            int gcol = tx * FTILE + c - 1;
            float v = 0.f;
            if (src != nullptr && (unsigned)grow < (unsigned)HH && (unsigned)gcol < (unsigned)WW)
                v = src[ic * HW + grow * WW + gcol];
            tile[i] = v;
        }
    };
    auto accum = [&](const float* __restrict__ Wbase, int wic, int icbase, bool isX) {
        const int c0 = cg * FCG;
        #pragma unroll 1
        for (int ic = 0; ic < FNSTG; ++ic) {
            float v[9];
            #pragma unroll
            for (int dy = 0; dy < 3; ++dy)
                #pragma unroll
                for (int dx = 0; dx < 3; ++dx)
                    v[dy * 3 + dx] = tile[(ic * FPADT + (ly + dy)) * FPADT + (lx + dx)];
            #pragma unroll
            for (int cc = 0; cc < FCG; ++cc) {
                const float* wr = Wbase + ((size_t)((0 * HID + c0 + cc) * wic + icbase + ic)) * 9;
                const float* wz = Wbase + ((size_t)((1 * HID + c0 + cc) * wic + icbase + ic)) * 9;
                const float* wn = Wbase + ((size_t)((2 * HID + c0 + cc) * wic + icbase + ic)) * 9;
                float r = 0.f, z = 0.f, n = 0.f;
                #pragma unroll
                for (int k = 0; k < 9; ++k) { r += v[k]*wr[k]; z += v[k]*wz[k]; n += v[k]*wn[k]; }
                accR[cc] += r; accZ[cc] += z;
                if (isX) accIN[cc] += n; else accHN[cc] += n;
            }
        }
    };

    const float* xb = x + ((size_t)b * T_ + t) * CIN * HW;
    stage(xb); __syncthreads();
    accum(Wi, CIN, 0, true); __syncthreads();

    const float* hb = (hprev_base != nullptr)
        ? hprev_base + ((size_t)b * T_ + (t - 1)) * HID * HW : nullptr;
    stage(hb); __syncthreads();
    accum(Wh, HID, 0, false); __syncthreads();
    stage(hb ? hb + (size_t)FNSTG * HW : nullptr); __syncthreads();
    accum(Wh, HID, FNSTG, false);

    float* ho = hout_base + ((size_t)b * T_ + t) * HID * HW;
    #pragma unroll
    for (int cc = 0; cc < FCG; ++cc) {
        const int c = cg * FCG + cc;
        float r = 1.f / (1.f + expf(-accR[cc]));
        float z = 1.f / (1.f + expf(-accZ[cc]));
        float n = tanhf(accIN[cc] + r * accHN[cc]);
        float hv = (hb != nullptr) ? hb[(size_t)c * HW + gy * WW + gx] : 0.f;
        ho[(size_t)c * HW + gy * WW + gx] = (1.f - z) * n + z * hv;
    }
}

extern "C" void kernel_launch(void* const* d_in, const int* in_sizes, int n_in,
                              void* d_out, int out_size, void* d_ws, size_t ws_size,
                              hipStream_t stream) {
    const float* x  = (const float*)d_in[0];
    const float* Wi = (const float*)d_in[1];
    const float* Wh = (const float*)d_in[2];
    float* out = (float*)d_out;

    if (ws_size >= (size_t)ATOTAL * 2) {
        unsigned short* A2 = (unsigned short*)d_ws;
        wconv<<<(ATOTAL + 255) / 256, 256, 0, stream>>>(Wi, Wh, A2);
        for (int t = 0; t < T_; ++t)
            convgru_mfma<<<dim3(32, 4, 4), 256, 0, stream>>>(x, A2, out, out, t);
    } else {
        for (int t = 0; t < T_; ++t) {
            const float* hprev = (t == 0) ? nullptr : out;
            convgru_step<<<dim3(4, 4, 32), dim3(16, 16), 0, stream>>>(x, Wi, Wh, hprev, out, t);
        }
    }
}

// Round 5
// 261.250 us; speedup vs baseline: 14.7335x; 1.5232x over previous
//
#include <hip/hip_runtime.h>
#include <math.h>

// Problem dims
constexpr int B_  = 4;
constexpr int T_  = 16;
constexpr int CIN = 32;
constexpr int HID = 64;
constexpr int HH  = 64;
constexpr int WW  = 64;
constexpr int HW  = HH * WW; // 4096

// ---------------- MFMA path config ----------------
constexpr int TR = 8,  TC = 16;         // output pixel tile: 8 rows x 16 cols
constexpr int PR = TR + 2, PC = TC + 2; // 10 x 18 (halo)
constexpr int CPAD = 40;                // channel slots per pixel (80B)
constexpr int KCH = 32;                 // channels per K-chunk
constexpr int AROWS = 48;               // 3 gates x 16 hidden rows
constexpr int AROWB = 640;              // A row stride bytes (5x128, XOR-closed)
constexpr int ASLAB_HW = AROWS * (AROWB/2);   // 15360 halfwords per (chunk,hg) slab
constexpr int ATOTAL = 3 * 4 * AROWS * 9 * KCH; // 165888 weight elements
constexpr int TIN_GRAN = PR * PC * CPAD * 2 / 16; // 900 16B granules per chunk
constexpr int A_GRAN   = AROWS * AROWB / 16;      // 1920 16B granules

// padded transposed image: [66][66][40] bf16 per (b,t) or (b,chunk)
constexpr int PIMG_HW = 66 * 66 * 40;   // 174240 halfwords

// ws layout (halfword offsets)
constexpr size_t A2_OFF  = 0;
constexpr size_t A2_HW   = 12 * ASLAB_HW;            // 184320
constexpr size_t XT_OFF  = A2_HW;                    // 184320
constexpr size_t XT_HW   = (size_t)64 * PIMG_HW;     // 11151360
constexpr size_t HT_OFF  = XT_OFF + XT_HW;           // 11335680
constexpr size_t HT_HW   = (size_t)8 * PIMG_HW;      // 2 bufs x 4 b x 2 chunks... (2*4*2? no: 2 bufs * 4b * 2ch = 16? see below)
// hT buffer: per buf: [b][chunk][66][66][40] = 8 * PIMG_HW? b(4)*chunk(2) = 8 images
constexpr size_t HTBUF_HW = (size_t)8 * PIMG_HW;     // 1393920... 8*174240 = 1393920
constexpr size_t WS_NEED_BYTES = (A2_HW + XT_HW + 2 * HTBUF_HW) * 2; // 28,247,040

typedef __attribute__((ext_vector_type(8))) short bf16x8;
typedef __attribute__((ext_vector_type(4))) float f32x4;

__device__ inline unsigned short f2bf(float f) {
    union { float f; unsigned u; } v; v.f = f;
    return (unsigned short)((v.u + 0x7FFFu + ((v.u >> 16) & 1u)) >> 16);
}

// ---- prepass 1: weights -> bf16, pre-swizzled 640B rows: [ch][hg] slab, row=gt*16+m ----
__global__ void wconv(const float* __restrict__ Wi, const float* __restrict__ Wh,
                      unsigned short* __restrict__ A2) {
    int idx = blockIdx.x * 256 + threadIdx.x;
    if (idx >= ATOTAL) return;
    int ic  = idx & 31;
    int r1  = idx >> 5;
    int tap = r1 % 9;
    int r2  = r1 / 9;
    int m   = r2 & 15;
    int r3  = r2 >> 4;
    int gt  = r3 % 3;
    int r4  = r3 / 3;
    int hg  = r4 & 3;
    int ch  = r4 >> 2;
    int o   = gt * 64 + hg * 16 + m;
    float w = (ch == 0) ? Wi[(o * CIN + ic) * 9 + tap]
                        : Wh[(o * HID + (ch - 1) * 32 + ic) * 9 + tap];
    int row = gt * 16 + m;
    int kb  = tap * 64 + ic * 2;   // packed byte offset in 576B logical row
    int dst = (ch * 4 + hg) * (ASLAB_HW * 2) + row * AROWB
            + ((kb & ~15) ^ ((row & 7) << 4)) + (kb & 15);
    *(unsigned short*)((char*)A2 + dst) = f2bf(w);
}

// ---- prepass 2: x -> channel-last padded bf16 xT[bt][66][66][40] ----
__global__ void xfill(const float* __restrict__ x, unsigned short* __restrict__ xT) {
    int riT = blockIdx.x;            // 0..65
    int bt  = blockIdx.y;            // 0..63
    unsigned short* dst = xT + (size_t)bt * PIMG_HW + riT * (66 * CPAD);
    for (int e = threadIdx.x; e < 66 * CPAD; e += 256) {
        int slot = e / 66;
        int ciT  = e - slot * 66;
        unsigned short v = 0;
        if (slot < 32 && riT >= 1 && riT <= 64 && ciT >= 1 && ciT <= 64)
            v = f2bf(x[((size_t)bt * 32 + slot) * HW + (riT - 1) * WW + (ciT - 1)]);
        dst[ciT * CPAD + slot] = v;
    }
}

// ---- prepass 3: zero both hT buffers ----
__global__ void hzero(unsigned short* __restrict__ hT, int n16) {
    int i = blockIdx.x * 256 + threadIdx.x;
    if (i < n16) ((f32x4*)hT)[i] = f32x4{0.f, 0.f, 0.f, 0.f};
}

// ---- fused ConvGRU step (MFMA). grid (32 tiles, 4 hg, 4 b), 256 thr ----
__global__ __launch_bounds__(256, 2) void convgru_mfma(
    const unsigned short* __restrict__ xT,   // [64][66][66][40]
    const unsigned short* __restrict__ A2,   // pre-swizzled slabs
    const unsigned short* __restrict__ hTrd, // [b][chunk][66][66][40] (t-1)
    unsigned short* __restrict__ hTwr,       // same layout (t)
    const float* hprev,                      // d_out base or null (fp32 h_{t-1})
    float* __restrict__ out, int t)
{
    __shared__ __align__(16) unsigned short tin[2][PR * PC * CPAD]; // 2 x 14400 B
    __shared__ __align__(16) unsigned short Al[ASLAB_HW];           // 30720 B

    const int tid  = threadIdx.x;
    const int lane = tid & 63, wave = tid >> 6;
    const int px   = lane & 15, kl = lane >> 4;
    const int ty = blockIdx.x >> 2, tx = blockIdx.x & 3;
    const int hg = blockIdx.y, b = blockIdx.z;
    const int gy0 = ty * TR, gx0 = tx * TC;

    const int nch = (t > 0) ? 3 : 1;

    f32x4 accR[2] = {}, accZ[2] = {}, accNX[2] = {}, accNH[2] = {};
    bf16x8 treg[4], areg[8];

    // tile-origin halfword offset inside a padded image (same for xT and hT chunks)
    const int rowbase = (ty * TR) * 66 + tx * TC; // pixel index of (r=0,c=0) granule row

    auto load_tin = [&](int ch) {
        const unsigned short* src = (ch == 0)
            ? (xT + (size_t)(b * T_ + t) * PIMG_HW)
            : (hTrd + (size_t)(b * 2 + (ch - 1)) * PIMG_HW);
        #pragma unroll
        for (int j = 0; j < 4; ++j) {
            int G = tid + j * 256;
            if (G < TIN_GRAN) {
                int r = G / 90, w = G - 90 * r;   // 90 granules per halo row
                treg[j] = *(const bf16x8*)(src + (rowbase + r * 66) * CPAD + w * 8);
            }
        }
    };
    auto write_tin = [&](int buf) {
        #pragma unroll
        for (int j = 0; j < 4; ++j) {
            int G = tid + j * 256;
            if (G < TIN_GRAN) *(bf16x8*)(&tin[buf][G * 8]) = treg[j];
        }
    };
    auto load_A = [&](int ch) {
        const unsigned short* s = A2 + (size_t)(ch * 4 + hg) * ASLAB_HW;
        #pragma unroll
        for (int j = 0; j < 8; ++j) {
            int v = tid + j * 256;
            if (v < A_GRAN) areg[j] = *(const bf16x8*)(s + v * 8);
        }
    };
    auto write_A = [&]() {
        #pragma unroll
        for (int j = 0; j < 8; ++j) {
            int v = tid + j * 256;
            if (v < A_GRAN) *(bf16x8*)(&Al[v * 8]) = areg[j];
        }
    };

    const int rb0 = ((wave * 2 + 0) * PC + px) * CPAD + kl * 8;
    const int rb1 = rb0 + PC * CPAD;
    const int swA = (px & 7) << 4;

    auto compute = [&](int buf, bool isX) {
        const unsigned short* tb = tin[buf];
        #pragma unroll
        for (int tap = 0; tap < 9; ++tap) {
            const int dy = tap / 3, dx = tap - 3 * dy;
            const int toff = (dy * PC + dx) * CPAD;
            bf16x8 b0 = *(const bf16x8*)(tb + rb0 + toff);
            bf16x8 b1 = *(const bf16x8*)(tb + rb1 + toff);
            const char* ab = (const char*)Al + px * AROWB + ((tap * 64 + kl * 16) ^ swA);
            bf16x8 ar = *(const bf16x8*)(ab);
            bf16x8 az = *(const bf16x8*)(ab + 16 * AROWB);
            bf16x8 an = *(const bf16x8*)(ab + 32 * AROWB);
            accR[0] = __builtin_amdgcn_mfma_f32_16x16x32_bf16(ar, b0, accR[0], 0, 0, 0);
            accR[1] = __builtin_amdgcn_mfma_f32_16x16x32_bf16(ar, b1, accR[1], 0, 0, 0);
            accZ[0] = __builtin_amdgcn_mfma_f32_16x16x32_bf16(az, b0, accZ[0], 0, 0, 0);
            accZ[1] = __builtin_amdgcn_mfma_f32_16x16x32_bf16(az, b1, accZ[1], 0, 0, 0);
            if (isX) {
                accNX[0] = __builtin_amdgcn_mfma_f32_16x16x32_bf16(an, b0, accNX[0], 0, 0, 0);
                accNX[1] = __builtin_amdgcn_mfma_f32_16x16x32_bf16(an, b1, accNX[1], 0, 0, 0);
            } else {
                accNH[0] = __builtin_amdgcn_mfma_f32_16x16x32_bf16(an, b0, accNH[0], 0, 0, 0);
                accNH[1] = __builtin_amdgcn_mfma_f32_16x16x32_bf16(an, b1, accNH[1], 0, 0, 0);
            }
        }
    };

    // ---- pipeline ----
    load_tin(0); load_A(0);
    write_tin(0); write_A();
    __syncthreads();
    for (int ch = 0; ch < nch; ++ch) {
        if (ch + 1 < nch) { load_tin(ch + 1); load_A(ch + 1); }
        compute(ch & 1, ch == 0);
        __syncthreads();
        if (ch + 1 < nch) { write_tin((ch + 1) & 1); write_A(); __syncthreads(); }
    }

    // ---- epilogue: gates + state update; write fp32 out + bf16 hT ----
    float* outp = out + ((size_t)(b * T_ + t)) * HID * HW;
    const float* hb = hprev ? (hprev + ((size_t)(b * T_ + t - 1)) * HID * HW) : nullptr;
    #pragma unroll
    for (int g = 0; g < 2; ++g) {
        int gy = gy0 + wave * 2 + g;
        int gx = gx0 + px;
        unsigned short hvals[4];
        #pragma unroll
        for (int q = 0; q < 4; ++q) {
            int c = hg * 16 + kl * 4 + q;
            float sr = 1.f / (1.f + expf(-accR[g][q]));
            float sz = 1.f / (1.f + expf(-accZ[g][q]));
            float nn = tanhf(accNX[g][q] + sr * accNH[g][q]);
            float hv = hb ? hb[(size_t)c * HW + gy * WW + gx] : 0.f;
            float hn = (1.f - sz) * nn + sz * hv;
            outp[(size_t)c * HW + gy * WW + gx] = hn;
            hvals[q] = f2bf(hn);
        }
        // hT write: chunk = c>>5, slot = c&31 (4 consecutive slots)
        int c0 = hg * 16 + kl * 4;
        unsigned short* hd = hTwr + (size_t)(b * 2 + (c0 >> 5)) * PIMG_HW
                           + ((gy + 1) * 66 + (gx + 1)) * CPAD + (c0 & 31);
        *(uint2*)hd = *(const uint2*)hvals;
    }
}

// ================= round-4 fallback (known-pass) =================
constexpr int R4_ASLAB = AROWS * 9 * KCH;      // 13824 hw packed
constexpr int R4_AVEC  = R4_ASLAB / 8;         // 1728
__global__ void wconv_r4(const float* __restrict__ Wi, const float* __restrict__ Wh,
                         unsigned short* __restrict__ A2) {
    int idx = blockIdx.x * 256 + threadIdx.x;
    if (idx >= ATOTAL) return;
    int ic = idx & 31; int r1 = idx >> 5;
    int tap = r1 % 9; int r2 = r1 / 9;
    int m = r2 & 15; int r3 = r2 >> 4;
    int gt = r3 % 3; int r4 = r3 / 3;
    int hg = r4 & 3; int ch = r4 >> 2;
    int o = gt * 64 + hg * 16 + m;
    float w = (ch == 0) ? Wi[(o * CIN + ic) * 9 + tap]
                        : Wh[(o * HID + (ch - 1) * 32 + ic) * 9 + tap];
    A2[idx] = f2bf(w);
}
__global__ __launch_bounds__(256, 2) void convgru_r4(
    const float* __restrict__ x, const unsigned short* __restrict__ A2,
    const float* hall, float* out, int t)
{
    __shared__ __align__(16) unsigned short tin[PR * PC * CPAD];
    __shared__ __align__(16) unsigned short Al[AROWS * (AROWB / 2)];
    const int tid = threadIdx.x;
    const int lane = tid & 63, wave = tid >> 6;
    const int px = lane & 15, kl = lane >> 4;
    const int ty = blockIdx.x >> 2, tx = blockIdx.x & 3;
    const int hg = blockIdx.y, b = blockIdx.z;
    const int gy0 = ty * TR, gx0 = tx * TC;
    const int nch = (t > 0) ? 3 : 1;
    const float* hb = (t > 0) ? (hall + ((size_t)(b * T_ + t - 1)) * HID * HW) : nullptr;
    const float* xb = x + ((size_t)(b * T_ + t)) * CIN * HW;
    f32x4 accR[2] = {}, accZ[2] = {}, accNX[2] = {}, accNH[2] = {};
    float ireg[23]; bf16x8 areg[7];
    auto load_in = [&](int ch) {
        const float* src = (ch == 0) ? xb : (hb + (size_t)(ch - 1) * KCH * HW);
        #pragma unroll
        for (int j = 0; j < 23; ++j) {
            int e = tid + j * 256; float v = 0.f;
            if (e < PR * PC * KCH) {
                int ic = e / (PR * PC); int rem = e - ic * (PR * PC);
                int r = rem / PC, c = rem - r * PC;
                int gy = gy0 + r - 1, gx = gx0 + c - 1;
                if ((unsigned)gy < (unsigned)HH && (unsigned)gx < (unsigned)WW)
                    v = src[ic * HW + gy * WW + gx];
            }
            ireg[j] = v;
        }
    };
    auto load_Ar = [&](int ch) {
        const unsigned short* s = A2 + (size_t)(ch * 4 + hg) * R4_ASLAB;
        #pragma unroll
        for (int j = 0; j < 7; ++j) { int v = tid + j * 256; if (v < R4_AVEC) areg[j] = *(const bf16x8*)(s + v * 8); }
    };
    auto write_in = [&]() {
        #pragma unroll
        for (int j = 0; j < 23; ++j) {
            int e = tid + j * 256;
            if (e < PR * PC * KCH) {
                int ic = e / (PR * PC); int rem = e - ic * (PR * PC);
                int r = rem / PC, c = rem - r * PC;
                tin[(r * PC + c) * CPAD + ic] = f2bf(ireg[j]);
            }
        }
    };
    auto write_Ar = [&]() {
        #pragma unroll
        for (int j = 0; j < 7; ++j) {
            int v = tid + j * 256;
            if (v < R4_AVEC) {
                int row = v / 36; int kb = (v - row * 36) * 16;
                char* dst = (char*)Al + row * AROWB + (kb ^ ((row & 7) << 4));
                *(bf16x8*)dst = areg[j];
            }
        }
    };
    const int rb0 = ((wave * 2 + 0) * PC + px) * CPAD + kl * 8;
    const int rb1 = rb0 + PC * CPAD;
    const int swA = (px & 7) << 4;
    auto compute = [&](bool isX) {
        #pragma unroll
        for (int tap = 0; tap < 9; ++tap) {
            const int dy = tap / 3, dx = tap - 3 * dy;
            const int toff = (dy * PC + dx) * CPAD;
            bf16x8 b0 = *(const bf16x8*)(tin + rb0 + toff);
            bf16x8 b1 = *(const bf16x8*)(tin + rb1 + toff);
            const char* ab = (const char*)Al + px * AROWB + ((tap * 64 + kl * 16) ^ swA);
            bf16x8 ar = *(const bf16x8*)(ab);
            bf16x8 az = *(const bf16x8*)(ab + 16 * AROWB);
            bf16x8 an = *(const bf16x8*)(ab + 32 * AROWB);
            accR[0] = __builtin_amdgcn_mfma_f32_16x16x32_bf16(ar, b0, accR[0], 0, 0, 0);
            accR[1] = __builtin_amdgcn_mfma_f32_16x16x32_bf16(ar, b1, accR[1], 0, 0, 0);
            accZ[0] = __builtin_amdgcn_mfma_f32_16x16x32_bf16(az, b0, accZ[0], 0, 0, 0);
            accZ[1] = __builtin_amdgcn_mfma_f32_16x16x32_bf16(az, b1, accZ[1], 0, 0, 0);
            if (isX) {
                accNX[0] = __builtin_amdgcn_mfma_f32_16x16x32_bf16(an, b0, accNX[0], 0, 0, 0);
                accNX[1] = __builtin_amdgcn_mfma_f32_16x16x32_bf16(an, b1, accNX[1], 0, 0, 0);
            } else {
                accNH[0] = __builtin_amdgcn_mfma_f32_16x16x32_bf16(an, b0, accNH[0], 0, 0, 0);
                accNH[1] = __builtin_amdgcn_mfma_f32_16x16x32_bf16(an, b1, accNH[1], 0, 0, 0);
            }
        }
    };
    load_in(0); load_Ar(0); write_in(); write_Ar();
    __syncthreads();
    for (int ch = 0; ch < nch; ++ch) {
        if (ch + 1 < nch) { load_in(ch + 1); load_Ar(ch + 1); }
        compute(ch == 0);
        __syncthreads();
        if (ch + 1 < nch) { write_in(); write_Ar(); __syncthreads(); }
    }
    float* outp = out + ((size_t)(b * T_ + t)) * HID * HW;
    #pragma unroll
    for (int g = 0; g < 2; ++g) {
        int gy = gy0 + wave * 2 + g; int gx = gx0 + px;
        #pragma unroll
        for (int q = 0; q < 4; ++q) {
            int c = hg * 16 + kl * 4 + q;
            float sr = 1.f / (1.f + expf(-accR[g][q]));
            float sz = 1.f / (1.f + expf(-accZ[g][q]));
            float nn = tanhf(accNX[g][q] + sr * accNH[g][q]);
            float hv = hb ? hb[(size_t)c * HW + gy * WW + gx] : 0.f;
            outp[(size_t)c * HW + gy * WW + gx] = (1.f - sz) * nn + sz * hv;
        }
    }
}

extern "C" void kernel_launch(void* const* d_in, const int* in_sizes, int n_in,
                              void* d_out, int out_size, void* d_ws, size_t ws_size,
                              hipStream_t stream) {
    const float* x  = (const float*)d_in[0];
    const float* Wi = (const float*)d_in[1];
    const float* Wh = (const float*)d_in[2];
    float* out = (float*)d_out;

    if (ws_size >= WS_NEED_BYTES) {
        unsigned short* A2  = (unsigned short*)d_ws;
        unsigned short* xT  = A2 + XT_OFF;
        unsigned short* hT0 = A2 + HT_OFF;
        unsigned short* hT1 = hT0 + HTBUF_HW;

        wconv<<<(ATOTAL + 255) / 256, 256, 0, stream>>>(Wi, Wh, A2);
        xfill<<<dim3(66, 64), 256, 0, stream>>>(x, xT);
        {
            int n16 = (int)(2 * HTBUF_HW / 8); // 16B granules
            hzero<<<(n16 + 255) / 256, 256, 0, stream>>>(hT0, n16);
        }
        for (int t = 0; t < T_; ++t) {
            unsigned short* rd = (t & 1) ? hT1 : hT0;
            unsigned short* wr = (t & 1) ? hT0 : hT1;
            const float* hprev = (t == 0) ? nullptr : out;
            convgru_mfma<<<dim3(32, 4, 4), 256, 0, stream>>>(xT, A2, rd, wr, hprev, out, t);
        }
    } else {
        unsigned short* A2 = (unsigned short*)d_ws;
        wconv_r4<<<(ATOTAL + 255) / 256, 256, 0, stream>>>(Wi, Wh, A2);
        for (int t = 0; t < T_; ++t)
            convgru_r4<<<dim3(32, 4, 4), 256, 0, stream>>>(x, A2, out, out, t);
    }
}

// Round 6
// 209.778 us; speedup vs baseline: 18.3486x; 1.2454x over previous
//
#include <hip/hip_runtime.h>
#include <math.h>

// Problem dims
constexpr int B_  = 4;
constexpr int T_  = 16;
constexpr int CIN = 32;
constexpr int HID = 64;
constexpr int HH  = 64;
constexpr int WW  = 64;
constexpr int HW  = HH * WW; // 4096

// ---------------- MFMA path config ----------------
constexpr int TR = 8,  TC = 16;         // output pixel tile: 8 rows x 16 cols
constexpr int PR = TR + 2, PC = TC + 2; // 10 x 18 (halo)
constexpr int CPAD = 40;                // channel slots per pixel (80B)
constexpr int KCH = 32;                 // channels per K-chunk
constexpr int AROWS = 48;               // 3 gates x 16 hidden rows
constexpr int AROWB = 640;              // A row stride bytes (5x128, XOR-closed)
constexpr int ASLAB_HW = AROWS * (AROWB/2);   // 15360 halfwords per (chunk,hg) slab
constexpr int ATOTAL = 3 * 4 * AROWS * 9 * KCH; // 165888 weight elements
constexpr int TIN_GRAN = PR * PC * CPAD * 2 / 16; // 900 16B granules per chunk
constexpr int A_GRAN   = AROWS * AROWB / 16;      // 1920 16B granules

// padded transposed image: [66][66][40] bf16 per (b,t) or (b,chunk)
constexpr int PIMG_HW = 66 * 66 * 40;   // 174240 halfwords

// ws layout (halfword offsets)
constexpr size_t A2_HW   = 12 * ASLAB_HW;            // 184320
constexpr size_t XT_OFF  = A2_HW;
constexpr size_t XT_HW   = (size_t)64 * PIMG_HW;
constexpr size_t HT_OFF  = XT_OFF + XT_HW;
constexpr size_t HTBUF_HW = (size_t)8 * PIMG_HW;     // [b(4)][chunk(2)] images
constexpr size_t WS_NEED_BYTES = (A2_HW + XT_HW + 2 * HTBUF_HW) * 2;

typedef __attribute__((ext_vector_type(8))) short bf16x8;
typedef __attribute__((ext_vector_type(4))) float f32x4;

#define GLOAD_LDS16(gsrc, ldst) \
  __builtin_amdgcn_global_load_lds((const __attribute__((address_space(1))) void*)(gsrc), \
                                   (__attribute__((address_space(3))) void*)(ldst), 16, 0, 0)

__device__ inline unsigned short f2bf(float f) {
    union { float f; unsigned u; } v; v.f = f;
    return (unsigned short)((v.u + 0x7FFFu + ((v.u >> 16) & 1u)) >> 16);
}

// ---- prepass 1: weights -> bf16, pre-swizzled 640B rows: [ch][hg] slab, row=gt*16+m ----
__global__ void wconv(const float* __restrict__ Wi, const float* __restrict__ Wh,
                      unsigned short* __restrict__ A2) {
    int idx = blockIdx.x * 256 + threadIdx.x;
    if (idx >= ATOTAL) return;
    int ic  = idx & 31;
    int r1  = idx >> 5;
    int tap = r1 % 9;
    int r2  = r1 / 9;
    int m   = r2 & 15;
    int r3  = r2 >> 4;
    int gt  = r3 % 3;
    int r4  = r3 / 3;
    int hg  = r4 & 3;
    int ch  = r4 >> 2;
    int o   = gt * 64 + hg * 16 + m;
    float w = (ch == 0) ? Wi[(o * CIN + ic) * 9 + tap]
                        : Wh[(o * HID + (ch - 1) * 32 + ic) * 9 + tap];
    int row = gt * 16 + m;
    int kb  = tap * 64 + ic * 2;   // packed byte offset in 576B logical row
    int dst = (ch * 4 + hg) * (ASLAB_HW * 2) + row * AROWB
            + ((kb & ~15) ^ ((row & 7) << 4)) + (kb & 15);
    *(unsigned short*)((char*)A2 + dst) = f2bf(w);
}

// ---- prepass 2 (coalesced): x -> channel-last padded bf16 xT[bt][66][66][40] ----
// block per (padded row riT, bt). Coalesced reads, LDS transpose, coalesced 16B writes.
__global__ void xfill(const float* __restrict__ x, unsigned short* __restrict__ xT) {
    const int riT = blockIdx.x;   // 0..65
    const int bt  = blockIdx.y;   // 0..63
    unsigned short* dst = xT + ((size_t)bt * 66 + riT) * (66 * CPAD);
    __shared__ float lds[64 * 41];

    if (riT >= 1 && riT <= 64) {
        const float* src = x + (size_t)bt * 32 * HW + (riT - 1) * WW;
        const int p = threadIdx.x & 63;
        #pragma unroll
        for (int j = 0; j < 8; ++j) {
            int c = j * 4 + (threadIdx.x >> 6);
            lds[p * 41 + c] = src[c * HW + p];   // coalesced 256B reads
        }
        __syncthreads();
        for (int g = threadIdx.x; g < 330; g += 256) {     // 66 px x 5 slot-groups
            int px = g / 5, s = g - px * 5;
            bf16x8 vv;
            #pragma unroll
            for (int k = 0; k < 8; ++k) {
                int slot = s * 8 + k;
                float v = 0.f;
                if (slot < 32 && px >= 1 && px <= 64) v = lds[(px - 1) * 41 + slot];
                vv[k] = (short)f2bf(v);
            }
            *(bf16x8*)(dst + g * 8) = vv;                  // coalesced 16B writes
        }
    } else {
        bf16x8 z = {};
        for (int g = threadIdx.x; g < 330; g += 256)
            *(bf16x8*)(dst + g * 8) = z;
    }
}

// ---- prepass 3: zero both hT buffers ----
__global__ void hzero(unsigned short* __restrict__ hT, int n16) {
    int i = blockIdx.x * 256 + threadIdx.x;
    if (i < n16) ((f32x4*)hT)[i] = f32x4{0.f, 0.f, 0.f, 0.f};
}

// ---- fused ConvGRU step (MFMA, global_load_lds staging) ----
// grid (32 tiles, 4 hg, 4 b), 256 thr
__global__ __launch_bounds__(256, 2) void convgru_mfma(
    const unsigned short* __restrict__ xT,   // [64][66][66][40]
    const unsigned short* __restrict__ A2,   // pre-swizzled slabs
    const unsigned short* __restrict__ hTrd, // [b][chunk][66][66][40] (t-1)
    unsigned short* __restrict__ hTwr,       // same layout (t)
    const float* hprev,                      // d_out base or null (fp32 h_{t-1})
    float* __restrict__ out, int t)
{
    __shared__ __align__(16) unsigned short tin[2][PR * PC * CPAD]; // 2 x 14400 B
    __shared__ __align__(16) unsigned short Al[ASLAB_HW];           // 30720 B

    const int tid  = threadIdx.x;
    const int lane = tid & 63, wave = tid >> 6;
    const int px   = lane & 15, kl = lane >> 4;
    const int ty = blockIdx.x >> 2, tx = blockIdx.x & 3;
    const int hg = blockIdx.y, b = blockIdx.z;
    const int gy0 = ty * TR, gx0 = tx * TC;

    const int nch = (t > 0) ? 3 : 1;
    const unsigned short* xs = xT + (size_t)(b * T_ + t) * PIMG_HW;

    f32x4 accR[2] = {}, accZ[2] = {}, accNX[2] = {}, accNH[2] = {};

    // tile-origin pixel index inside a padded image
    const int rowbase = (ty * TR) * 66 + tx * TC;

    auto stage_tin = [&](int ch, int buf) {
        const unsigned short* src = (ch == 0)
            ? xs : (hTrd + (size_t)(b * 2 + (ch - 1)) * PIMG_HW);
        #pragma unroll
        for (int j = 0; j < 4; ++j) {
            int G = tid + j * 256;
            if (G < TIN_GRAN) {
                int r = G / 90, w = G - 90 * r;   // 90 granules per halo row
                GLOAD_LDS16(src + (rowbase + r * 66) * CPAD + w * 8, &tin[buf][G * 8]);
            }
        }
    };
    auto stage_A = [&](int ch) {
        const unsigned short* s = A2 + (size_t)(ch * 4 + hg) * ASLAB_HW;
        #pragma unroll
        for (int j = 0; j < 8; ++j) {
            int v = tid + j * 256;
            if (v < A_GRAN) GLOAD_LDS16(s + v * 8, &Al[v * 8]);
        }
    };

    const int rb0 = ((wave * 2 + 0) * PC + px) * CPAD + kl * 8;
    const int rb1 = rb0 + PC * CPAD;
    const int swA = (px & 7) << 4;

    auto compute = [&](int buf, bool isX) {
        const unsigned short* tb = tin[buf];
        #pragma unroll
        for (int tap = 0; tap < 9; ++tap) {
            const int dy = tap / 3, dx = tap - 3 * dy;
            const int toff = (dy * PC + dx) * CPAD;
            bf16x8 b0 = *(const bf16x8*)(tb + rb0 + toff);
            bf16x8 b1 = *(const bf16x8*)(tb + rb1 + toff);
            const char* ab = (const char*)Al + px * AROWB + ((tap * 64 + kl * 16) ^ swA);
            bf16x8 ar = *(const bf16x8*)(ab);
            bf16x8 az = *(const bf16x8*)(ab + 16 * AROWB);
            bf16x8 an = *(const bf16x8*)(ab + 32 * AROWB);
            accR[0] = __builtin_amdgcn_mfma_f32_16x16x32_bf16(ar, b0, accR[0], 0, 0, 0);
            accR[1] = __builtin_amdgcn_mfma_f32_16x16x32_bf16(ar, b1, accR[1], 0, 0, 0);
            accZ[0] = __builtin_amdgcn_mfma_f32_16x16x32_bf16(az, b0, accZ[0], 0, 0, 0);
            accZ[1] = __builtin_amdgcn_mfma_f32_16x16x32_bf16(az, b1, accZ[1], 0, 0, 0);
            if (isX) {
                accNX[0] = __builtin_amdgcn_mfma_f32_16x16x32_bf16(an, b0, accNX[0], 0, 0, 0);
                accNX[1] = __builtin_amdgcn_mfma_f32_16x16x32_bf16(an, b1, accNX[1], 0, 0, 0);
            } else {
                accNH[0] = __builtin_amdgcn_mfma_f32_16x16x32_bf16(an, b0, accNH[0], 0, 0, 0);
                accNH[1] = __builtin_amdgcn_mfma_f32_16x16x32_bf16(an, b1, accNH[1], 0, 0, 0);
            }
        }
    };

    // ---- pipeline: DMA staging, tin double-buffered, A single-buffered ----
    stage_tin(0, 0); stage_A(0);
    __syncthreads();                       // drains vmcnt before barrier
    for (int ch = 0; ch < nch; ++ch) {
        if (ch + 1 < nch) stage_tin(ch + 1, (ch + 1) & 1);  // prefetch under compute
        compute(ch & 1, ch == 0);
        __syncthreads();
        if (ch + 1 < nch) { stage_A(ch + 1); __syncthreads(); }
    }

    // ---- epilogue: gates + state update; write fp32 out + bf16 hT ----
    float* outp = out + ((size_t)(b * T_ + t)) * HID * HW;
    const float* hb = hprev ? (hprev + ((size_t)(b * T_ + t - 1)) * HID * HW) : nullptr;
    #pragma unroll
    for (int g = 0; g < 2; ++g) {
        int gy = gy0 + wave * 2 + g;
        int gx = gx0 + px;
        unsigned short hvals[4];
        #pragma unroll
        for (int q = 0; q < 4; ++q) {
            int c = hg * 16 + kl * 4 + q;
            float sr = 1.f / (1.f + expf(-accR[g][q]));
            float sz = 1.f / (1.f + expf(-accZ[g][q]));
            float nn = tanhf(accNX[g][q] + sr * accNH[g][q]);
            float hv = hb ? hb[(size_t)c * HW + gy * WW + gx] : 0.f;
            float hn = (1.f - sz) * nn + sz * hv;
            outp[(size_t)c * HW + gy * WW + gx] = hn;
            hvals[q] = f2bf(hn);
        }
        int c0 = hg * 16 + kl * 4;
        unsigned short* hd = hTwr + (size_t)(b * 2 + (c0 >> 5)) * PIMG_HW
                           + ((gy + 1) * 66 + (gx + 1)) * CPAD + (c0 & 31);
        *(uint2*)hd = *(const uint2*)hvals;
    }
}

// ================= round-4 fallback (known-pass, tiny ws) =================
constexpr int R4_ASLAB = AROWS * 9 * KCH;
constexpr int R4_AVEC  = R4_ASLAB / 8;
__global__ void wconv_r4(const float* __restrict__ Wi, const float* __restrict__ Wh,
                         unsigned short* __restrict__ A2) {
    int idx = blockIdx.x * 256 + threadIdx.x;
    if (idx >= ATOTAL) return;
    int ic = idx & 31; int r1 = idx >> 5;
    int tap = r1 % 9; int r2 = r1 / 9;
    int m = r2 & 15; int r3 = r2 >> 4;
    int gt = r3 % 3; int r4 = r3 / 3;
    int hg = r4 & 3; int ch = r4 >> 2;
    int o = gt * 64 + hg * 16 + m;
    float w = (ch == 0) ? Wi[(o * CIN + ic) * 9 + tap]
                        : Wh[(o * HID + (ch - 1) * 32 + ic) * 9 + tap];
    A2[idx] = f2bf(w);
}
__global__ __launch_bounds__(256, 2) void convgru_r4(
    const float* __restrict__ x, const unsigned short* __restrict__ A2,
    const float* hall, float* out, int t)
{
    __shared__ __align__(16) unsigned short tin[PR * PC * CPAD];
    __shared__ __align__(16) unsigned short Al[AROWS * (AROWB / 2)];
    const int tid = threadIdx.x;
    const int lane = tid & 63, wave = tid >> 6;
    const int px = lane & 15, kl = lane >> 4;
    const int ty = blockIdx.x >> 2, tx = blockIdx.x & 3;
    const int hg = blockIdx.y, b = blockIdx.z;
    const int gy0 = ty * TR, gx0 = tx * TC;
    const int nch = (t > 0) ? 3 : 1;
    const float* hb = (t > 0) ? (hall + ((size_t)(b * T_ + t - 1)) * HID * HW) : nullptr;
    const float* xb = x + ((size_t)(b * T_ + t)) * CIN * HW;
    f32x4 accR[2] = {}, accZ[2] = {}, accNX[2] = {}, accNH[2] = {};
    float ireg[23]; bf16x8 areg[7];
    auto load_in = [&](int ch) {
        const float* src = (ch == 0) ? xb : (hb + (size_t)(ch - 1) * KCH * HW);
        #pragma unroll
        for (int j = 0; j < 23; ++j) {
            int e = tid + j * 256; float v = 0.f;
            if (e < PR * PC * KCH) {
                int ic = e / (PR * PC); int rem = e - ic * (PR * PC);
                int r = rem / PC, c = rem - r * PC;
                int gy = gy0 + r - 1, gx = gx0 + c - 1;
                if ((unsigned)gy < (unsigned)HH && (unsigned)gx < (unsigned)WW)
                    v = src[ic * HW + gy * WW + gx];
            }
            ireg[j] = v;
        }
    };
    auto load_Ar = [&](int ch) {
        const unsigned short* s = A2 + (size_t)(ch * 4 + hg) * R4_ASLAB;
        #pragma unroll
        for (int j = 0; j < 7; ++j) { int v = tid + j * 256; if (v < R4_AVEC) areg[j] = *(const bf16x8*)(s + v * 8); }
    };
    auto write_in = [&]() {
        #pragma unroll
        for (int j = 0; j < 23; ++j) {
            int e = tid + j * 256;
            if (e < PR * PC * KCH) {
                int ic = e / (PR * PC); int rem = e - ic * (PR * PC);
                int r = rem / PC, c = rem - r * PC;
                tin[(r * PC + c) * CPAD + ic] = f2bf(ireg[j]);
            }
        }
    };
    auto write_Ar = [&]() {
        #pragma unroll
        for (int j = 0; j < 7; ++j) {
            int v = tid + j * 256;
            if (v < R4_AVEC) {
                int row = v / 36; int kb = (v - row * 36) * 16;
                char* dst = (char*)Al + row * AROWB + (kb ^ ((row & 7) << 4));
                *(bf16x8*)dst = areg[j];
            }
        }
    };
    const int rb0 = ((wave * 2 + 0) * PC + px) * CPAD + kl * 8;
    const int rb1 = rb0 + PC * CPAD;
    const int swA = (px & 7) << 4;
    auto compute = [&](bool isX) {
        #pragma unroll
        for (int tap = 0; tap < 9; ++tap) {
            const int dy = tap / 3, dx = tap - 3 * dy;
            const int toff = (dy * PC + dx) * CPAD;
            bf16x8 b0 = *(const bf16x8*)(tin + rb0 + toff);
            bf16x8 b1 = *(const bf16x8*)(tin + rb1 + toff);
            const char* ab = (const char*)Al + px * AROWB + ((tap * 64 + kl * 16) ^ swA);
            bf16x8 ar = *(const bf16x8*)(ab);
            bf16x8 az = *(const bf16x8*)(ab + 16 * AROWB);
            bf16x8 an = *(const bf16x8*)(ab + 32 * AROWB);
            accR[0] = __builtin_amdgcn_mfma_f32_16x16x32_bf16(ar, b0, accR[0], 0, 0, 0);
            accR[1] = __builtin_amdgcn_mfma_f32_16x16x32_bf16(ar, b1, accR[1], 0, 0, 0);
            accZ[0] = __builtin_amdgcn_mfma_f32_16x16x32_bf16(az, b0, accZ[0], 0, 0, 0);
            accZ[1] = __builtin_amdgcn_mfma_f32_16x16x32_bf16(az, b1, accZ[1], 0, 0, 0);
            if (isX) {
                accNX[0] = __builtin_amdgcn_mfma_f32_16x16x32_bf16(an, b0, accNX[0], 0, 0, 0);
                accNX[1] = __builtin_amdgcn_mfma_f32_16x16x32_bf16(an, b1, accNX[1], 0, 0, 0);
            } else {
                accNH[0] = __builtin_amdgcn_mfma_f32_16x16x32_bf16(an, b0, accNH[0], 0, 0, 0);
                accNH[1] = __builtin_amdgcn_mfma_f32_16x16x32_bf16(an, b1, accNH[1], 0, 0, 0);
            }
        }
    };
    load_in(0); load_Ar(0); write_in(); write_Ar();
    __syncthreads();
    for (int ch = 0; ch < nch; ++ch) {
        if (ch + 1 < nch) { load_in(ch + 1); load_Ar(ch + 1); }
        compute(ch == 0);
        __syncthreads();
        if (ch + 1 < nch) { write_in(); write_Ar(); __syncthreads(); }
    }
    float* outp = out + ((size_t)(b * T_ + t)) * HID * HW;
    #pragma unroll
    for (int g = 0; g < 2; ++g) {
        int gy = gy0 + wave * 2 + g; int gx = gx0 + px;
        #pragma unroll
        for (int q = 0; q < 4; ++q) {
            int c = hg * 16 + kl * 4 + q;
            float sr = 1.f / (1.f + expf(-accR[g][q]));
            float sz = 1.f / (1.f + expf(-accZ[g][q]));
            float nn = tanhf(accNX[g][q] + sr * accNH[g][q]);
            float hv = hb ? hb[(size_t)c * HW + gy * WW + gx] : 0.f;
            outp[(size_t)c * HW + gy * WW + gx] = (1.f - sz) * nn + sz * hv;
        }
    }
}

extern "C" void kernel_launch(void* const* d_in, const int* in_sizes, int n_in,
                              void* d_out, int out_size, void* d_ws, size_t ws_size,
                              hipStream_t stream) {
    const float* x  = (const float*)d_in[0];
    const float* Wi = (const float*)d_in[1];
    const float* Wh = (const float*)d_in[2];
    float* out = (float*)d_out;

    if (ws_size >= WS_NEED_BYTES) {
        unsigned short* A2  = (unsigned short*)d_ws;
        unsigned short* xT  = A2 + XT_OFF;
        unsigned short* hT0 = A2 + HT_OFF;
        unsigned short* hT1 = hT0 + HTBUF_HW;

        wconv<<<(ATOTAL + 255) / 256, 256, 0, stream>>>(Wi, Wh, A2);
        xfill<<<dim3(66, 64), 256, 0, stream>>>(x, xT);
        {
            int n16 = (int)(2 * HTBUF_HW / 8);
            hzero<<<(n16 + 255) / 256, 256, 0, stream>>>(hT0, n16);
        }
        for (int t = 0; t < T_; ++t) {
            unsigned short* rd = (t & 1) ? hT1 : hT0;
            unsigned short* wr = (t & 1) ? hT0 : hT1;
            const float* hprev = (t == 0) ? nullptr : out;
            convgru_mfma<<<dim3(32, 4, 4), 256, 0, stream>>>(xT, A2, rd, wr, hprev, out, t);
        }
    } else {
        unsigned short* A2 = (unsigned short*)d_ws;
        wconv_r4<<<(ATOTAL + 255) / 256, 256, 0, stream>>>(Wi, Wh, A2);
        for (int t = 0; t < T_; ++t)
            convgru_r4<<<dim3(32, 4, 32), dim3(16, 16), 0, stream>>>(x, A2, out, out, t);
    }
}